// Round 6
// baseline (12925.272 us; speedup 1.0000x reference)
//
#include <hip/hip_runtime.h>
#include <hip/hip_fp16.h>
#include <stdint.h>

// LSTM-like scan, T=4096, E=1024, H=1024.
// Phase 1: xpre4[t][row][g] = (x @ U_g^T + B_g)  fp16, gate-interleaved
// Phase 2: persistent 64-WG x 512-thread kernel, 16 rows/WG.
//   Weights live in AGPRs: 64 dwords/lane parked once via inline-asm
//   v_accvgpr_write_b32 ("=a"). Inline-asm defs are NOT rematerializable and
//   AGPR pressure (64) + VGPR working set (~75) is far under budget, so the
//   allocator must keep them resident — this is the residency mechanism the
//   compiler cannot defeat (rounds 1-5 showed loads always get remat'd/spilled).
//   Per step: 64 volatile v_accvgpr_read + 64 v_dot2 from registers.
//   h broadcast: ((epoch)<<16)|fp16 tagged dwords, double-buffered by parity;
//   wave 0 polls with global_load_dwordx4 sc0 sc1 (+s_sleep backoff), packs
//   pairs into LDS; ONE barrier/step; in-half shfl reduce; chunk-leader lane
//   does the epilogue and publishes via agent-scope store.

#define T_STEPS 4096
#define HDIM 1024
#define NWG 64

typedef _Float16 half2v __attribute__((ext_vector_type(2)));
typedef uint32_t u32x4 __attribute__((ext_vector_type(4)));

__device__ __forceinline__ float dot2(uint32_t a, uint32_t b, float c) {
#if __has_builtin(__builtin_amdgcn_fdot2)
  return __builtin_amdgcn_fdot2(__builtin_bit_cast(half2v, a),
                                __builtin_bit_cast(half2v, b), c, false);
#else
  half2v av = __builtin_bit_cast(half2v, a);
  half2v bv = __builtin_bit_cast(half2v, b);
  return c + (float)av.x * (float)bv.x + (float)av.y * (float)bv.y;
#endif
}

__device__ __forceinline__ float sigf(float z) { return 1.f / (1.f + __expf(-z)); }

// ---- weight repack: gate f32 [1024][1024] x4 -> per-lane-packed fp16 dwords ----
// Lane lg = wg*512+tid: row = (wg<<4)+(tid>>5), k = tid&31.
// Lane block = 64 dwords: i = g*16 + ic, covering cols 32k+2*ic, +1.
__global__ __launch_bounds__(256) void convw(const float* __restrict__ w0,
                                             const float* __restrict__ w1,
                                             const float* __restrict__ w2,
                                             const float* __restrict__ w3,
                                             uint32_t* __restrict__ dst) {
  int o = blockIdx.x * 256 + threadIdx.x;  // 0 .. 2M-1 output dwords
  int i = o & 63;
  int lg = o >> 6;
  int wg = lg >> 9, tidl = lg & 511;
  int k = tidl & 31, rloc = tidl >> 5;
  int row = (wg << 4) + rloc;
  int g = i >> 4, ic = i & 15;
  int col = (k << 5) + (ic << 1);
  const float* src = g == 0 ? w0 : g == 1 ? w1 : g == 2 ? w2 : w3;
  float2 v = *(const float2*)(src + (size_t)row * 1024 + col);
  uint32_t dw = (uint32_t)__half_as_ushort(__float2half(v.x)) |
                ((uint32_t)__half_as_ushort(__float2half(v.y)) << 16);
  dst[o] = dw;
}

// ---------------- zero the tagged h broadcast buffers (2 x 1024 dwords) --------
__global__ void zerok(uint32_t* __restrict__ p) {
  int i = blockIdx.x * 256 + threadIdx.x;
  if (i < 2048) p[i] = 0;
}

// ---------------- fp32 GEMM: xpre4[t][j][g] = x[t][:] . U_g[j][:] + B_g[j] -----
__global__ __launch_bounds__(256) void gemmk(
    const float* __restrict__ x,
    const float* __restrict__ u0, const float* __restrict__ u1,
    const float* __restrict__ u2, const float* __restrict__ u3,
    const float* __restrict__ b0, const float* __restrict__ b1,
    const float* __restrict__ b2, const float* __restrict__ b3,
    __half* __restrict__ xpre4) {
  __shared__ float As[64][33];
  __shared__ float Bs[64][33];
  const int tid = threadIdx.x;
  const int m0 = blockIdx.y * 64;
  const int n0 = blockIdx.x * 64;
  const int g = n0 >> 10;
  const float* Up = g == 0 ? u0 : g == 1 ? u1 : g == 2 ? u2 : u3;
  const float* Bp = g == 0 ? b0 : g == 1 ? b1 : g == 2 ? b2 : b3;
  const int j0 = n0 & 1023;
  const int tx = tid & 15, ty = tid >> 4;
  const int lr = tid >> 3, lc = (tid & 7) << 2;
  float acc[4][4] = {};
  for (int k0 = 0; k0 < 1024; k0 += 32) {
    float4 a0 = *(const float4*)&x[(size_t)(m0 + lr) * 1024 + k0 + lc];
    float4 a1 = *(const float4*)&x[(size_t)(m0 + lr + 32) * 1024 + k0 + lc];
    float4 c0 = *(const float4*)&Up[(size_t)(j0 + lr) * 1024 + k0 + lc];
    float4 c1 = *(const float4*)&Up[(size_t)(j0 + lr + 32) * 1024 + k0 + lc];
    __syncthreads();
    As[lr][lc + 0] = a0.x; As[lr][lc + 1] = a0.y; As[lr][lc + 2] = a0.z; As[lr][lc + 3] = a0.w;
    As[lr + 32][lc + 0] = a1.x; As[lr + 32][lc + 1] = a1.y; As[lr + 32][lc + 2] = a1.z; As[lr + 32][lc + 3] = a1.w;
    Bs[lr][lc + 0] = c0.x; Bs[lr][lc + 1] = c0.y; Bs[lr][lc + 2] = c0.z; Bs[lr][lc + 3] = c0.w;
    Bs[lr + 32][lc + 0] = c1.x; Bs[lr + 32][lc + 1] = c1.y; Bs[lr + 32][lc + 2] = c1.z; Bs[lr + 32][lc + 3] = c1.w;
    __syncthreads();
#pragma unroll
    for (int k = 0; k < 32; ++k) {
      float a0v = As[ty * 4 + 0][k], a1v = As[ty * 4 + 1][k];
      float a2v = As[ty * 4 + 2][k], a3v = As[ty * 4 + 3][k];
      float b0v = Bs[tx * 4 + 0][k], b1v = Bs[tx * 4 + 1][k];
      float b2v = Bs[tx * 4 + 2][k], b3v = Bs[tx * 4 + 3][k];
      acc[0][0] += a0v * b0v; acc[0][1] += a0v * b1v; acc[0][2] += a0v * b2v; acc[0][3] += a0v * b3v;
      acc[1][0] += a1v * b0v; acc[1][1] += a1v * b1v; acc[1][2] += a1v * b2v; acc[1][3] += a1v * b3v;
      acc[2][0] += a2v * b0v; acc[2][1] += a2v * b1v; acc[2][2] += a2v * b2v; acc[2][3] += a2v * b3v;
      acc[3][0] += a3v * b0v; acc[3][1] += a3v * b1v; acc[3][2] += a3v * b2v; acc[3][3] += a3v * b3v;
    }
  }
  // scatter epilogue: xpre4[(t*1024 + j)*4 + g]
#pragma unroll
  for (int i = 0; i < 4; ++i) {
    size_t rowi = (size_t)(m0 + ty * 4 + i);
#pragma unroll
    for (int j = 0; j < 4; ++j) {
      int jj = j0 + tx * 4 + j;
      float v = acc[i][j] + Bp[jj];
      xpre4[(rowi * 1024 + jj) * 4 + g] = __float2half(v);
    }
  }
}

// ---------------- persistent recurrence kernel --------------------------------
__global__ __launch_bounds__(512, 1) void rnnk(
    const uint32_t* __restrict__ wpack,  // [64][512][64] dwords, per-lane packed
    const __half* __restrict__ xpre4,    // [4096][1024][4] fp16
    uint32_t* tagged,                    // [2][1024] tagged h dwords
    float* __restrict__ out) {           // [4096][1024] f32
  __shared__ uint32_t hl[2][640];        // packed h pairs, stride-20 chunks
  const int wg = blockIdx.x;
  const int tid = threadIdx.x;
  const int wave = tid >> 6, lane = tid & 63;
  const int k = tid & 31;            // h-chunk: cols [32k, 32k+32)
  const int rloc = tid >> 5;         // 0..15
  const int row = (wg << 4) + rloc;  // 0..1023
  const bool w0 = (wave == 0);
  const bool leader = (k == 0);

  // ---- load this lane's 64 weight dwords and PARK THEM IN AGPRS ----
  // asm defs are opaque: not rematerializable, so they stay resident.
  uint32_t wa[64];
  {
    const u32x4* wp = reinterpret_cast<const u32x4*>(wpack) +
                      (((size_t)wg << 9) + (size_t)tid) * 16;
#pragma unroll
    for (int j = 0; j < 16; ++j) {
      u32x4 w4 = wp[j];
      asm("v_accvgpr_write_b32 %0, %4\n\t"
          "v_accvgpr_write_b32 %1, %5\n\t"
          "v_accvgpr_write_b32 %2, %6\n\t"
          "v_accvgpr_write_b32 %3, %7"
          : "=a"(wa[4 * j + 0]), "=a"(wa[4 * j + 1]),
            "=a"(wa[4 * j + 2]), "=a"(wa[4 * j + 3])
          : "v"(w4.x), "v"(w4.y), "v"(w4.z), "v"(w4.w));
    }
  }

  float s = 0.f;  // cell state (leader lanes only)

  for (int t = 0; t < T_STEPS; ++t) {
    const int buf = t & 1;

    // leader prefetch: all 4 gate pre-activations in ONE 8B load
    float xf = 0.f, xc = 0.f, xg = 0.f, xq = 0.f;
    if (leader) {
      uint2 xv = *reinterpret_cast<const uint2*>(
          reinterpret_cast<const uint32_t*>(xpre4) +
          ((((size_t)t << 10) + row) << 1));
      __half2 lo = __builtin_bit_cast(__half2, xv.x);
      __half2 hi = __builtin_bit_cast(__half2, xv.y);
      xf = __half2float(lo.x); xc = __half2float(lo.y);
      xg = __half2float(hi.x); xq = __half2float(hi.y);
    }

    // --- wave 0: poll h_{t-1} (16 tagged dwords/lane via 4x dwordx4 sc0 sc1) ---
    if (w0) {
      const uint32_t* tb = tagged + (buf << 10) + (lane << 4);
      const uint32_t tg = (uint32_t)t;
      u32x4 v0, v1, v2, v3;
      bool ok;
      do {
        asm volatile(
            "global_load_dwordx4 %0, %4, off sc0 sc1\n\t"
            "global_load_dwordx4 %1, %5, off sc0 sc1\n\t"
            "global_load_dwordx4 %2, %6, off sc0 sc1\n\t"
            "global_load_dwordx4 %3, %7, off sc0 sc1\n\t"
            "s_waitcnt vmcnt(0)"
            : "=&v"(v0), "=&v"(v1), "=&v"(v2), "=&v"(v3)
            : "v"(tb), "v"(tb + 4), "v"(tb + 8), "v"(tb + 12)
            : "memory");
        ok = (v0.x >> 16) == tg && (v0.y >> 16) == tg && (v0.z >> 16) == tg &&
             (v0.w >> 16) == tg && (v1.x >> 16) == tg && (v1.y >> 16) == tg &&
             (v1.z >> 16) == tg && (v1.w >> 16) == tg && (v2.x >> 16) == tg &&
             (v2.y >> 16) == tg && (v2.z >> 16) == tg && (v2.w >> 16) == tg &&
             (v3.x >> 16) == tg && (v3.y >> 16) == tg && (v3.z >> 16) == tg &&
             (v3.w >> 16) == tg;
        if (!ok) __builtin_amdgcn_s_sleep(1);  // damp L3 poll traffic
      } while (!ok);
      // pack 16 tagged dwords -> 8 fp16-pair dwords; p = 8*lane + j
      uint32_t pk[8];
      pk[0] = (v0.x & 0xffffu) | (v0.y << 16);
      pk[1] = (v0.z & 0xffffu) | (v0.w << 16);
      pk[2] = (v1.x & 0xffffu) | (v1.y << 16);
      pk[3] = (v1.z & 0xffffu) | (v1.w << 16);
      pk[4] = (v2.x & 0xffffu) | (v2.y << 16);
      pk[5] = (v2.z & 0xffffu) | (v2.w << 16);
      pk[6] = (v3.x & 0xffffu) | (v3.y << 16);
      pk[7] = (v3.z & 0xffffu) | (v3.w << 16);
      // dst: chunk c = p>>4 = lane>>1, idx = p&15 = 8*(lane&1)+j, stride 20
      uint32_t* dst = &hl[buf][20 * (lane >> 1) + ((lane & 1) << 3)];
      u32x4 wA, wB;
      wA.x = pk[0]; wA.y = pk[1]; wA.z = pk[2]; wA.w = pk[3];
      wB.x = pk[4]; wB.y = pk[5]; wB.z = pk[6]; wB.w = pk[7];
      *reinterpret_cast<u32x4*>(dst) = wA;
      *reinterpret_cast<u32x4*>(dst + 4) = wB;
    }
    __syncthreads();  // hl[buf] ready — the only barrier per step

    // --- own h chunk: 4 quads at stride-20 (bank-spread; halves broadcast) ---
    u32x4 hq[4];
#pragma unroll
    for (int m = 0; m < 4; ++m)
      hq[m] = *reinterpret_cast<const u32x4*>(&hl[buf][20 * k + (m << 2)]);

    // --- 4 gates x 32 MACs; weights pulled from AGPRs just-in-time.
    // volatile reads: LICM must not hoist them into 64 pre-loop VGPR copies.
    float a0 = 0.f, a1 = 0.f, a2 = 0.f, a3 = 0.f;
#pragma unroll
    for (int m = 0; m < 4; ++m) {
      uint32_t wf0, wf1, wf2, wf3, wc0, wc1, wc2, wc3;
      uint32_t wg0, wg1, wg2, wg3, wq0, wq1, wq2, wq3;
      asm volatile(
          "v_accvgpr_read_b32 %0, %8\n\t"
          "v_accvgpr_read_b32 %1, %9\n\t"
          "v_accvgpr_read_b32 %2, %10\n\t"
          "v_accvgpr_read_b32 %3, %11\n\t"
          "v_accvgpr_read_b32 %4, %12\n\t"
          "v_accvgpr_read_b32 %5, %13\n\t"
          "v_accvgpr_read_b32 %6, %14\n\t"
          "v_accvgpr_read_b32 %7, %15"
          : "=v"(wf0), "=v"(wf1), "=v"(wf2), "=v"(wf3),
            "=v"(wc0), "=v"(wc1), "=v"(wc2), "=v"(wc3)
          : "a"(wa[(m << 2) + 0]), "a"(wa[(m << 2) + 1]),
            "a"(wa[(m << 2) + 2]), "a"(wa[(m << 2) + 3]),
            "a"(wa[16 + (m << 2) + 0]), "a"(wa[16 + (m << 2) + 1]),
            "a"(wa[16 + (m << 2) + 2]), "a"(wa[16 + (m << 2) + 3]));
      asm volatile(
          "v_accvgpr_read_b32 %0, %8\n\t"
          "v_accvgpr_read_b32 %1, %9\n\t"
          "v_accvgpr_read_b32 %2, %10\n\t"
          "v_accvgpr_read_b32 %3, %11\n\t"
          "v_accvgpr_read_b32 %4, %12\n\t"
          "v_accvgpr_read_b32 %5, %13\n\t"
          "v_accvgpr_read_b32 %6, %14\n\t"
          "v_accvgpr_read_b32 %7, %15"
          : "=v"(wg0), "=v"(wg1), "=v"(wg2), "=v"(wg3),
            "=v"(wq0), "=v"(wq1), "=v"(wq2), "=v"(wq3)
          : "a"(wa[32 + (m << 2) + 0]), "a"(wa[32 + (m << 2) + 1]),
            "a"(wa[32 + (m << 2) + 2]), "a"(wa[32 + (m << 2) + 3]),
            "a"(wa[48 + (m << 2) + 0]), "a"(wa[48 + (m << 2) + 1]),
            "a"(wa[48 + (m << 2) + 2]), "a"(wa[48 + (m << 2) + 3]));
      // interleave the 4 accumulator chains for ILP
      a0 = dot2(wf0, hq[m].x, a0); a1 = dot2(wc0, hq[m].x, a1);
      a2 = dot2(wg0, hq[m].x, a2); a3 = dot2(wq0, hq[m].x, a3);
      a0 = dot2(wf1, hq[m].y, a0); a1 = dot2(wc1, hq[m].y, a1);
      a2 = dot2(wg1, hq[m].y, a2); a3 = dot2(wq1, hq[m].y, a3);
      a0 = dot2(wf2, hq[m].z, a0); a1 = dot2(wc2, hq[m].z, a1);
      a2 = dot2(wg2, hq[m].z, a2); a3 = dot2(wq2, hq[m].z, a3);
      a0 = dot2(wf3, hq[m].w, a0); a1 = dot2(wc3, hq[m].w, a1);
      a2 = dot2(wg3, hq[m].w, a2); a3 = dot2(wq3, hq[m].w, a3);
    }

    // --- reduce across the 32 chunk-lanes of this row (stays in 32-lane half) ---
#pragma unroll
    for (int mk = 1; mk <= 16; mk <<= 1) {
      a0 += __shfl_xor(a0, mk);
      a1 += __shfl_xor(a1, mk);
      a2 += __shfl_xor(a2, mk);
      a3 += __shfl_xor(a3, mk);
    }

    // --- leader epilogue: gates, s-update, h, publish ---
    if (leader) {
      float f = sigf(a0 + xf);
      float cc = sigf(a1 + xc);
      float gg = sigf(a2 + xg);
      float q = sigf(a3 + xq);
      s = f * s + gg * cc;
      float e2 = __expf(2.f * s);  // s >= 0 always; inf -> th = 1
      float th = 1.f - 2.f / (e2 + 1.f);
      float h = th * q;
      out[(size_t)t * HDIM + row] = h;
      uint32_t dw = ((uint32_t)(t + 1) << 16) |
                    (uint32_t)__half_as_ushort(__float2half(h));
      __hip_atomic_store(&tagged[(((t + 1) & 1) << 10) + row], dw,
                         __ATOMIC_RELAXED, __HIP_MEMORY_SCOPE_AGENT);
    }
    // no trailing barrier: wave0's next hl write targets hl[buf^1] (last read
    // at step t-1, done before this step's barrier), and its poll for t+1
    // succeeds only after every row published t+1.
  }
}

extern "C" void kernel_launch(void* const* d_in, const int* in_sizes, int n_in,
                              void* d_out, int out_size, void* d_ws, size_t ws_size,
                              hipStream_t stream) {
  const float* x  = (const float*)d_in[0];
  const float* Uf = (const float*)d_in[1];
  const float* Wf = (const float*)d_in[2];
  const float* Bf = (const float*)d_in[3];
  const float* Ug = (const float*)d_in[4];
  const float* Wg = (const float*)d_in[5];
  const float* Bg = (const float*)d_in[6];
  const float* Uq = (const float*)d_in[7];
  const float* Wq = (const float*)d_in[8];
  const float* Bq = (const float*)d_in[9];
  const float* U  = (const float*)d_in[10];
  const float* W  = (const float*)d_in[11];
  const float* B  = (const float*)d_in[12];
  float* out = (float*)d_out;

  // ws layout: [0,32MB) xpre4 fp16 [4096][1024][4]; [32MB,40MB) wpack 2M dwords;
  // [40MB,+8KB) tagged h dwords [2][1024].
  char* ws = (char*)d_ws;
  __half* xpre4 = (__half*)ws;
  uint32_t* wpack = (uint32_t*)(ws + (size_t)32 * 1024 * 1024);
  uint32_t* tagged = (uint32_t*)(ws + (size_t)40 * 1024 * 1024);

  // gate order everywhere: 0=f(Uf,Wf,Bf) 1=c(U,W,B) 2=g(Ug,Wg,Bg) 3=q(Uq,Wq,Bq)
  convw<<<8192, 256, 0, stream>>>(Wf, W, Wg, Wq, wpack);
  zerok<<<8, 256, 0, stream>>>(tagged);
  gemmk<<<dim3(64, 64), 256, 0, stream>>>(x, Uf, U, Ug, Uq, Bf, B, Bg, Bq, xpre4);
  rnnk<<<NWG, 512, 0, stream>>>(wpack, xpre4, tagged, out);
}

// Round 7
// 11941.202 us; speedup vs baseline: 1.0824x; 1.0824x over previous
//
#include <hip/hip_runtime.h>
#include <hip/hip_fp16.h>
#include <stdint.h>

// LSTM-like scan, T=4096, E=1024, H=1024.
// Phase 1: xpre4[t][row][g] = (x @ U_g^T + B_g)  fp16, gate-interleaved
// Phase 2: persistent 64-WG x 512-thread kernel, 16 rows/WG, self-poll sync.
//   Per step and per lane (row = wg*16 + tid/32, chunk k = tid%32):
//     1. issue 16 coalesced global_load_dwordx4 of this lane's 64 weight
//        dwords (asm volatile, no wait) — streams 128 KB/CU from L2
//     2. poll OWN u64 tagged pair (sc0 sc1 + vmcnt(0)): the wait for the
//        publishers also drains the weight loads -> full overlap
//     3. write packed pair to LDS, one barrier
//     4. 16x ds_read_b32 at lane-stride-32 (bank = k, conflict-free),
//        64 v_dot2 against the register-resident weights
//     5. 5-level shfl_xor reduce in 32-lane halves; k==0 leader does gates,
//        s-update, tanh, out-store, and publishes tagged h for t+1.
//   Tagged word = ((t+1)<<16) | fp16(h), double-buffered by epoch parity.

#define T_STEPS 4096
#define HDIM 1024
#define NWG 64

typedef _Float16 half2v __attribute__((ext_vector_type(2)));
typedef uint32_t u32x4 __attribute__((ext_vector_type(4)));

__device__ __forceinline__ float dot2(uint32_t a, uint32_t b, float c) {
#if __has_builtin(__builtin_amdgcn_fdot2)
  return __builtin_amdgcn_fdot2(__builtin_bit_cast(half2v, a),
                                __builtin_bit_cast(half2v, b), c, false);
#else
  half2v av = __builtin_bit_cast(half2v, a);
  half2v bv = __builtin_bit_cast(half2v, b);
  return c + (float)av.x * (float)bv.x + (float)av.y * (float)bv.y;
#endif
}

__device__ __forceinline__ float sigf(float z) { return 1.f / (1.f + __expf(-z)); }

// ---- weight repack: gate f32 [1024][1024] x4 -> rnnk's coalesced layout ----
// dst dword index o = ((wg*16 + j)*512 + tid)*4 + e :
//   lane (wg,tid): k=tid&31, rloc=tid>>5, row=wg*16+rloc
//   logical weight dword i = 4j+e in [0,64): gate g=i>>4, n=i&15,
//   h-pair p = k + 32n  -> cols 2p, 2p+1 of gate-g weight row `row`.
__global__ __launch_bounds__(256) void convw(const float* __restrict__ w0,
                                             const float* __restrict__ w1,
                                             const float* __restrict__ w2,
                                             const float* __restrict__ w3,
                                             uint32_t* __restrict__ dst) {
  int o = blockIdx.x * 256 + threadIdx.x;  // 0 .. 2M-1
  int e = o & 3;
  int tid = (o >> 2) & 511;
  int j = (o >> 11) & 15;
  int wg = o >> 15;
  int i = 4 * j + e;
  int g = i >> 4, n = i & 15;
  int k = tid & 31, rloc = tid >> 5;
  int row = (wg << 4) + rloc;
  int col = ((k + (n << 5)) << 1);
  const float* src = g == 0 ? w0 : g == 1 ? w1 : g == 2 ? w2 : w3;
  float2 v = *(const float2*)(src + (size_t)row * 1024 + col);
  dst[o] = (uint32_t)__half_as_ushort(__float2half(v.x)) |
           ((uint32_t)__half_as_ushort(__float2half(v.y)) << 16);
}

// ---------------- zero the tagged h broadcast buffers (2 x 1024 dwords) --------
__global__ void zerok(uint32_t* __restrict__ p) {
  int i = blockIdx.x * 256 + threadIdx.x;
  if (i < 2048) p[i] = 0;
}

// ---------------- fp32 GEMM: xpre4[t][j][g] = x[t][:] . U_g[j][:] + B_g[j] -----
__global__ __launch_bounds__(256) void gemmk(
    const float* __restrict__ x,
    const float* __restrict__ u0, const float* __restrict__ u1,
    const float* __restrict__ u2, const float* __restrict__ u3,
    const float* __restrict__ b0, const float* __restrict__ b1,
    const float* __restrict__ b2, const float* __restrict__ b3,
    __half* __restrict__ xpre4) {
  __shared__ float As[64][33];
  __shared__ float Bs[64][33];
  const int tid = threadIdx.x;
  const int m0 = blockIdx.y * 64;
  const int n0 = blockIdx.x * 64;
  const int g = n0 >> 10;
  const float* Up = g == 0 ? u0 : g == 1 ? u1 : g == 2 ? u2 : u3;
  const float* Bp = g == 0 ? b0 : g == 1 ? b1 : g == 2 ? b2 : b3;
  const int j0 = n0 & 1023;
  const int tx = tid & 15, ty = tid >> 4;
  const int lr = tid >> 3, lc = (tid & 7) << 2;
  float acc[4][4] = {};
  for (int k0 = 0; k0 < 1024; k0 += 32) {
    float4 a0 = *(const float4*)&x[(size_t)(m0 + lr) * 1024 + k0 + lc];
    float4 a1 = *(const float4*)&x[(size_t)(m0 + lr + 32) * 1024 + k0 + lc];
    float4 c0 = *(const float4*)&Up[(size_t)(j0 + lr) * 1024 + k0 + lc];
    float4 c1 = *(const float4*)&Up[(size_t)(j0 + lr + 32) * 1024 + k0 + lc];
    __syncthreads();
    As[lr][lc + 0] = a0.x; As[lr][lc + 1] = a0.y; As[lr][lc + 2] = a0.z; As[lr][lc + 3] = a0.w;
    As[lr + 32][lc + 0] = a1.x; As[lr + 32][lc + 1] = a1.y; As[lr + 32][lc + 2] = a1.z; As[lr + 32][lc + 3] = a1.w;
    Bs[lr][lc + 0] = c0.x; Bs[lr][lc + 1] = c0.y; Bs[lr][lc + 2] = c0.z; Bs[lr][lc + 3] = c0.w;
    Bs[lr + 32][lc + 0] = c1.x; Bs[lr + 32][lc + 1] = c1.y; Bs[lr + 32][lc + 2] = c1.z; Bs[lr + 32][lc + 3] = c1.w;
    __syncthreads();
#pragma unroll
    for (int k = 0; k < 32; ++k) {
      float a0v = As[ty * 4 + 0][k], a1v = As[ty * 4 + 1][k];
      float a2v = As[ty * 4 + 2][k], a3v = As[ty * 4 + 3][k];
      float b0v = Bs[tx * 4 + 0][k], b1v = Bs[tx * 4 + 1][k];
      float b2v = Bs[tx * 4 + 2][k], b3v = Bs[tx * 4 + 3][k];
      acc[0][0] += a0v * b0v; acc[0][1] += a0v * b1v; acc[0][2] += a0v * b2v; acc[0][3] += a0v * b3v;
      acc[1][0] += a1v * b0v; acc[1][1] += a1v * b1v; acc[1][2] += a1v * b2v; acc[1][3] += a1v * b3v;
      acc[2][0] += a2v * b0v; acc[2][1] += a2v * b1v; acc[2][2] += a2v * b2v; acc[2][3] += a2v * b3v;
      acc[3][0] += a3v * b0v; acc[3][1] += a3v * b1v; acc[3][2] += a3v * b2v; acc[3][3] += a3v * b3v;
    }
  }
  // scatter epilogue: xpre4[(t*1024 + j)*4 + g]
#pragma unroll
  for (int i = 0; i < 4; ++i) {
    size_t rowi = (size_t)(m0 + ty * 4 + i);
#pragma unroll
    for (int j = 0; j < 4; ++j) {
      int jj = j0 + tx * 4 + j;
      float v = acc[i][j] + Bp[jj];
      xpre4[(rowi * 1024 + jj) * 4 + g] = __float2half(v);
    }
  }
}

// ---------------- persistent recurrence kernel --------------------------------
__global__ __launch_bounds__(512, 1) void rnnk(
    const uint32_t* __restrict__ wpack,  // [64][16][512][4] dwords (see convw)
    const __half* __restrict__ xpre4,    // [4096][1024][4] fp16
    uint32_t* tagged,                    // [2][1024] tagged h dwords
    float* __restrict__ out) {           // [4096][1024] f32
  __shared__ uint32_t hl[2][512];        // packed h pairs, linear
  const int wg = blockIdx.x;
  const int tid = threadIdx.x;
  const int k = tid & 31;            // h-chunk lane
  const int rloc = tid >> 5;         // 0..15
  const int row = (wg << 4) + rloc;  // 0..1023
  const bool leader = (k == 0);

  const uint32_t* wbase = wpack + (((size_t)wg << 4) << 11) + (tid << 2);

  float s = 0.f;  // cell state (leader lanes only)

  for (int t = 0; t < T_STEPS; ++t) {
    const int buf = t & 1;

    // --- 1. issue this step's 16 weight loads (coalesced; no wait here) ---
    u32x4 wq[16];
#pragma unroll
    for (int j = 0; j < 16; ++j) {
      const uint32_t* p = wbase + (j << 11);
      asm volatile("global_load_dwordx4 %0, %1, off" : "=v"(wq[j]) : "v"(p));
    }

    // --- 2. leader prefetch of the 4 gate pre-activations (8B) ---
    float xf = 0.f, xc = 0.f, xg = 0.f, xq = 0.f;
    if (leader) {
      uint2 xv = *reinterpret_cast<const uint2*>(
          reinterpret_cast<const uint32_t*>(xpre4) +
          ((((size_t)t << 10) + row) << 1));
      __half2 lo = __builtin_bit_cast(__half2, xv.x);
      __half2 hi = __builtin_bit_cast(__half2, xv.y);
      xf = __half2float(lo.x); xc = __half2float(lo.y);
      xg = __half2float(hi.x); xq = __half2float(hi.y);
    }

    // --- 3. self-poll own tagged pair; vmcnt(0) also drains the weight loads ---
    {
      const unsigned long long* pp =
          reinterpret_cast<const unsigned long long*>(tagged + (buf << 10)) + tid;
      const uint32_t tg = (uint32_t)t;
      unsigned long long v;
      for (;;) {
        asm volatile(
            "global_load_dwordx2 %0, %1, off sc0 sc1\n\t"
            "s_waitcnt vmcnt(0)"
            : "=v"(v) : "v"(pp) : "memory");
        if ((((uint32_t)(v >> 16) & 0xffffu) == tg) && ((uint32_t)(v >> 48) == tg))
          break;
        __builtin_amdgcn_s_sleep(1);
      }
      hl[buf][tid] = (uint32_t)(v & 0xffffu) |
                     (((uint32_t)(v >> 32) & 0xffffu) << 16);
    }
    __syncthreads();  // hl[buf] ready — the only barrier per step

    // --- 4. h pairs at lane-stride 32 (bank = k: conflict-free) + 64 dot2 ---
    uint32_t hp[16];
#pragma unroll
    for (int n = 0; n < 16; ++n) hp[n] = hl[buf][k + (n << 5)];

#define WD(g, n) (wq[((g)*16 + (n)) >> 2][((g)*16 + (n)) & 3])
    float a0 = 0.f, a1 = 0.f, a2 = 0.f, a3 = 0.f;
#pragma unroll
    for (int n = 0; n < 16; ++n) {
      a0 = dot2(WD(0, n), hp[n], a0);
      a1 = dot2(WD(1, n), hp[n], a1);
      a2 = dot2(WD(2, n), hp[n], a2);
      a3 = dot2(WD(3, n), hp[n], a3);
    }
#undef WD

    // --- 5. reduce across the 32 chunk-lanes (stays within 32-lane halves) ---
#pragma unroll
    for (int mk = 1; mk <= 16; mk <<= 1) {
      a0 += __shfl_xor(a0, mk);
      a1 += __shfl_xor(a1, mk);
      a2 += __shfl_xor(a2, mk);
      a3 += __shfl_xor(a3, mk);
    }

    // --- leader epilogue: gates, s-update, h, publish ---
    if (leader) {
      float f = sigf(a0 + xf);
      float cc = sigf(a1 + xc);
      float gg = sigf(a2 + xg);
      float q = sigf(a3 + xq);
      s = f * s + gg * cc;
      float e2 = __expf(2.f * s);  // s >= 0 always; inf -> th = 1
      float th = 1.f - 2.f / (e2 + 1.f);
      float h = th * q;
      out[(size_t)t * HDIM + row] = h;
      uint32_t dw = ((uint32_t)(t + 1) << 16) |
                    (uint32_t)__half_as_ushort(__float2half(h));
      __hip_atomic_store(&tagged[(((t + 1) & 1) << 10) + row], dw,
                         __ATOMIC_RELAXED, __HIP_MEMORY_SCOPE_AGENT);
    }
    // no trailing barrier: writes to hl[buf] at t+2 are gated by the poll for
    // t+2, which succeeds only after all leaders published t+2, which requires
    // every thread to have passed barrier(t+1), i.e. finished reading hl[buf]
    // at step t.
  }
}

extern "C" void kernel_launch(void* const* d_in, const int* in_sizes, int n_in,
                              void* d_out, int out_size, void* d_ws, size_t ws_size,
                              hipStream_t stream) {
  const float* x  = (const float*)d_in[0];
  const float* Uf = (const float*)d_in[1];
  const float* Wf = (const float*)d_in[2];
  const float* Bf = (const float*)d_in[3];
  const float* Ug = (const float*)d_in[4];
  const float* Wg = (const float*)d_in[5];
  const float* Bg = (const float*)d_in[6];
  const float* Uq = (const float*)d_in[7];
  const float* Wq = (const float*)d_in[8];
  const float* Bq = (const float*)d_in[9];
  const float* U  = (const float*)d_in[10];
  const float* W  = (const float*)d_in[11];
  const float* B  = (const float*)d_in[12];
  float* out = (float*)d_out;

  // ws layout: [0,32MB) xpre4 fp16 [4096][1024][4]; [32MB,40MB) wpack 2M dwords;
  // [40MB,+8KB) tagged h dwords [2][1024].
  char* ws = (char*)d_ws;
  __half* xpre4 = (__half*)ws;
  uint32_t* wpack = (uint32_t*)(ws + (size_t)32 * 1024 * 1024);
  uint32_t* tagged = (uint32_t*)(ws + (size_t)40 * 1024 * 1024);

  // gate order everywhere: 0=f(Uf,Wf,Bf) 1=c(U,W,B) 2=g(Ug,Wg,Bg) 3=q(Uq,Wq,Bq)
  convw<<<8192, 256, 0, stream>>>(Wf, W, Wg, Wq, wpack);
  zerok<<<8, 256, 0, stream>>>(tagged);
  gemmk<<<dim3(64, 64), 256, 0, stream>>>(x, Uf, U, Ug, Uq, Bf, B, Bg, Bq, xpre4);
  rnnk<<<NWG, 512, 0, stream>>>(wpack, xpre4, tagged, out);
}